// Round 8
// baseline (156.539 us; speedup 1.0000x reference)
//
#include <hip/hip_runtime.h>

#define ROWS 1024
#define COLS 1024
#define NN (ROWS*COLS)

#define TILE_H 64
#define TILE_W 32
#define HALO   16              // steps fused per launch
#define RH     96              // TILE_H + 2*HALO
#define RW     64              // TILE_W + 2*HALO
#define RC     (RH*RW)         // 6144 cells
#define SPR    (RW/4)          // 16 float4-strips per region row
#define NSTRIP (RC/4)          // 1536
#define NT     384             // 6 waves; == number of 4x4 blocks
#define BR     (RH/4)          // 24 block-rows
#define BC     (RW/4)          // 16 block-cols

static constexpr float RHOG    = 1000.0f * 9.81f;
static constexpr float INV_SEC = 1.0f / 31556926.0f;
static constexpr float FLOWC   = 0.0405f;

__device__ __forceinline__ float4 gld4(const float* __restrict__ p, int g, bool in) {
    if (in) return *reinterpret_cast<const float4*>(p + g);
    return make_float4(0.f, 0.f, 0.f, 0.f);
}

// ---- prologue: phi, inv_total, runoff -------------------------------------
__global__ __launch_bounds__(256) void k_pre(
        const float* __restrict__ bed, const float* __restrict__ pw,
        const int* __restrict__ status,
        const float* __restrict__ melt, const float* __restrict__ area,
        float* __restrict__ phi, float* __restrict__ inv,
        float* __restrict__ runoff) {
    int i = blockIdx.x * 256 + threadIdx.x;
    int r = i >> 10, c = i & (COLS - 1);
    float p = RHOG * bed[i] + pw[i];
    float t = 0.f;
    if (c > 0)        t += fmaxf(p - (RHOG * bed[i - 1]    + pw[i - 1]),    0.f);
    if (c < COLS - 1) t += fmaxf(p - (RHOG * bed[i + 1]    + pw[i + 1]),    0.f);
    if (r > 0)        t += fmaxf(p - (RHOG * bed[i - COLS] + pw[i - COLS]), 0.f);
    if (r < ROWS - 1) t += fmaxf(p - (RHOG * bed[i + COLS] + pw[i + COLS]), 0.f);
    phi[i]    = p;
    inv[i]    = (status[i] == 0 && t > 0.f) ? (1.f / t) : 0.f;
    runoff[i] = melt[i] * area[i] * INV_SEC;
}

// ---- fused 16-step halo-tiled Jacobi, 4x4 cells/thread --------------------
// R7 post-mortem: default launch_bounds capped VGPRs at 80 < the ~150-reg
// working set (q16+ro16+w64+dd16) -> scratch spills -> latency-bound 57 us.
// __launch_bounds__(384, 3): 3 waves/SIMD = 2 six-wave blocks/CU (matches
// grid) and a ~170-VGPR cap that fits the working set with NO spills.
template <bool FIRST, bool FINAL>
__global__ __launch_bounds__(NT, 3) void k_fused(
        const float* __restrict__ phi_g, const float* __restrict__ inv_g,
        const float* __restrict__ run_g, const float* __restrict__ qin,
        float* __restrict__ qout,
        const float* __restrict__ cond, const int* __restrict__ status) {
    __shared__ __align__(16) char smem[8 * NT * 16];   // 49152 B, unioned
    float*  A   = (float*)smem;                        // phi staging [RC]
    float*  Bv  = A + RC;                              // inv staging [RC]
    float4* plT = (float4*)smem;                       // [2][NT] each
    float4* plB = plT + 2 * NT;
    float4* plL = plB + 2 * NT;
    float4* plR = plL + 2 * NT;

    const int tid = threadIdx.x;
    const int r0 = (int)blockIdx.y * TILE_H - HALO;
    const int c0 = (int)blockIdx.x * TILE_W - HALO;

    // phase 1: stage phi, inv (4 strips/thread)
#pragma unroll
    for (int k = 0; k < 4; ++k) {
        int sidx = tid + k * NT;
        int sr = sidx / SPR, sc4 = (sidx - sr * SPR) * 4;
        int gr = r0 + sr, gc = c0 + sc4;
        bool in = (gr >= 0) & (gr < ROWS) & (gc >= 0) & (gc < COLS);
        int g = gr * COLS + gc;
        *reinterpret_cast<float4*>(&A[sr * RW + sc4])  = gld4(phi_g, g, in);
        *reinterpret_cast<float4*>(&Bv[sr * RW + sc4]) = gld4(inv_g, g, in);
    }
    __syncthreads();

    const int br = tid / BC, bc = tid - (tid / BC) * BC;
    const int rr0 = 4 * br, cc0 = 4 * bc;
    const bool inter = (br >= HALO / 4) & (br < BR - HALO / 4) &
                       (bc >= HALO / 4) & (bc < BC - HALO / 4);

    float wW[4][4], wE[4][4], wN[4][4], wS[4][4];
    float q[4][4], ro[4][4];
    int dd[4][4];

    // phase 2: weights from LDS phi/inv into registers
#pragma unroll
    for (int i = 0; i < 4; ++i) {
        int rr = rr0 + i;
        int x = rr * RW + cc0;
        float4 pc = *reinterpret_cast<const float4*>(&A[x]);
        float4 ic = *reinterpret_cast<const float4*>(&Bv[x]);
        int xu = (rr > 0)      ? x - RW : x;
        int xd = (rr < RH - 1) ? x + RW : x;
        float4 pu = *reinterpret_cast<const float4*>(&A[xu]);
        float4 iu = *reinterpret_cast<const float4*>(&Bv[xu]);
        float4 pd = *reinterpret_cast<const float4*>(&A[xd]);
        float4 id = *reinterpret_cast<const float4*>(&Bv[xd]);
        float pl = (cc0 > 0)      ? A[x - 1]  : pc.x;
        float il = (cc0 > 0)      ? Bv[x - 1] : 0.f;
        float pr = (cc0 < RW - 4) ? A[x + 4]  : pc.w;
        float ir = (cc0 < RW - 4) ? Bv[x + 4] : 0.f;
        wN[i][0] = fmaxf(pu.x - pc.x, 0.f) * iu.x;
        wN[i][1] = fmaxf(pu.y - pc.y, 0.f) * iu.y;
        wN[i][2] = fmaxf(pu.z - pc.z, 0.f) * iu.z;
        wN[i][3] = fmaxf(pu.w - pc.w, 0.f) * iu.w;
        wS[i][0] = fmaxf(pd.x - pc.x, 0.f) * id.x;
        wS[i][1] = fmaxf(pd.y - pc.y, 0.f) * id.y;
        wS[i][2] = fmaxf(pd.z - pc.z, 0.f) * id.z;
        wS[i][3] = fmaxf(pd.w - pc.w, 0.f) * id.w;
        wW[i][0] = fmaxf(pl   - pc.x, 0.f) * il;
        wW[i][1] = fmaxf(pc.x - pc.y, 0.f) * ic.x;
        wW[i][2] = fmaxf(pc.y - pc.z, 0.f) * ic.y;
        wW[i][3] = fmaxf(pc.z - pc.w, 0.f) * ic.z;
        wE[i][0] = fmaxf(pc.y - pc.x, 0.f) * ic.y;
        wE[i][1] = fmaxf(pc.z - pc.y, 0.f) * ic.z;
        wE[i][2] = fmaxf(pc.w - pc.z, 0.f) * ic.w;
        wE[i][3] = fmaxf(pr   - pc.w, 0.f) * ir;
    }
#pragma unroll
    for (int i = 0; i < 4; ++i)
#pragma unroll
        for (int j = 0; j < 4; ++j) {
            int rr = rr0 + i, cc = cc0 + j;
            dd[i][j] = min(min(rr, RH - 1 - rr), min(cc, RW - 1 - cc));
        }
    // runoff + q0 straight from global to registers
#pragma unroll
    for (int i = 0; i < 4; ++i) {
        int gr = r0 + rr0 + i, gc = c0 + cc0;
        bool in = (gr >= 0) & (gr < ROWS) & (gc >= 0) & (gc < COLS);
        int g = gr * COLS + gc;
        float4 r4 = gld4(run_g, g, in);
        ro[i][0] = r4.x; ro[i][1] = r4.y; ro[i][2] = r4.z; ro[i][3] = r4.w;
        float4 q4 = FIRST ? r4 : gld4(qin, g, in);
        q[i][0] = q4.x; q[i][1] = q4.y; q[i][2] = q4.z; q[i][3] = q4.w;
    }
    __syncthreads();   // all phi/inv reads done — safe to overwrite with planes

    plT[tid]      = make_float4(q[0][0], q[0][1], q[0][2], q[0][3]);
    plB[tid]      = make_float4(q[3][0], q[3][1], q[3][2], q[3][3]);
    plL[tid]      = make_float4(q[0][0], q[1][0], q[2][0], q[3][0]);
    plR[tid]      = make_float4(q[0][3], q[1][3], q[2][3], q[3][3]);
    __syncthreads();

    // phase 3: 16 Jacobi steps; LDS only at block edges
    for (int s = 0; s < HALO; ++s) {
        const int pp = s & 1, pn = pp ^ 1;
        float4 up = plB[pp * NT + ((br > 0)      ? tid - BC : tid)];
        float4 dn = plT[pp * NT + ((br < BR - 1) ? tid + BC : tid)];
        float4 lf = plR[pp * NT + ((bc > 0)      ? tid - 1  : tid)];
        float4 rt = plL[pp * NT + ((bc < BC - 1) ? tid + 1  : tid)];
        float upv[4] = {up.x, up.y, up.z, up.w};
        float dnv[4] = {dn.x, dn.y, dn.z, dn.w};
        float lfv[4] = {lf.x, lf.y, lf.z, lf.w};
        float rtv[4] = {rt.x, rt.y, rt.z, rt.w};
        float nq[4][4];
#pragma unroll
        for (int i = 0; i < 4; ++i)
#pragma unroll
            for (int j = 0; j < 4; ++j) {
                float uv = (i > 0) ? q[i - 1][j] : upv[j];
                float dv = (i < 3) ? q[i + 1][j] : dnv[j];
                float lv = (j > 0) ? q[i][j - 1] : lfv[i];
                float rv = (j < 3) ? q[i][j + 1] : rtv[i];
                float a = ro[i][j];
                a = fmaf(wW[i][j], lv, a);
                a = fmaf(wE[i][j], rv, a);
                a = fmaf(wN[i][j], uv, a);
                a = fmaf(wS[i][j], dv, a);
                nq[i][j] = a;
            }
        if (!inter) {          // border blocks freeze cells past their depth
#pragma unroll
            for (int i = 0; i < 4; ++i)
#pragma unroll
                for (int j = 0; j < 4; ++j)
                    nq[i][j] = (s < dd[i][j]) ? nq[i][j] : q[i][j];
        }
#pragma unroll
        for (int i = 0; i < 4; ++i)
#pragma unroll
            for (int j = 0; j < 4; ++j) q[i][j] = nq[i][j];
        plT[pn * NT + tid] = make_float4(q[0][0], q[0][1], q[0][2], q[0][3]);
        plB[pn * NT + tid] = make_float4(q[3][0], q[3][1], q[3][2], q[3][3]);
        plL[pn * NT + tid] = make_float4(q[0][0], q[1][0], q[2][0], q[3][0]);
        plR[pn * NT + tid] = make_float4(q[0][3], q[1][3], q[2][3], q[3][3]);
        __syncthreads();
    }

    // phase 4: interior blocks == the 64x32 output tile exactly
    if (inter) {
#pragma unroll
        for (int i = 0; i < 4; ++i) {
            int g = (r0 + rr0 + i) * COLS + (c0 + cc0);
            if (FINAL) {
                float4 c4 = *reinterpret_cast<const float4*>(cond + g);
                int4 st   = *reinterpret_cast<const int4*>(status + g);
                float4 o;
                float t;
                t = q[i][0] * FLOWC * (c4.x * sqrtf(sqrtf(c4.x))); o.x = (st.x == 0) ? t * t : 0.f;
                t = q[i][1] * FLOWC * (c4.y * sqrtf(sqrtf(c4.y))); o.y = (st.y == 0) ? t * t : 0.f;
                t = q[i][2] * FLOWC * (c4.z * sqrtf(sqrtf(c4.z))); o.z = (st.z == 0) ? t * t : 0.f;
                t = q[i][3] * FLOWC * (c4.w * sqrtf(sqrtf(c4.w))); o.w = (st.w == 0) ? t * t : 0.f;
                *reinterpret_cast<float4*>(qout + g) = o;
            } else {
                *reinterpret_cast<float4*>(qout + g) =
                    make_float4(q[i][0], q[i][1], q[i][2], q[i][3]);
            }
        }
    }
}

extern "C" void kernel_launch(void* const* d_in, const int* in_sizes, int n_in,
                              void* d_out, int out_size, void* d_ws, size_t ws_size,
                              hipStream_t stream) {
    const float* melt   = (const float*)d_in[0];
    const float* bed    = (const float*)d_in[1];
    const float* pw     = (const float*)d_in[2];
    const float* area   = (const float*)d_in[3];
    const float* cond   = (const float*)d_in[4];
    const int*   status = (const int*)d_in[5];
    float* out = (float*)d_out;

    char* ws = (char*)d_ws;
    float* phi    = (float*)(ws);                 //  4 MB
    float* inv    = (float*)(ws + 4ull  * NN);    //  4 MB
    float* runoff = (float*)(ws + 8ull  * NN);    //  4 MB
    float* qA     = (float*)(ws + 12ull * NN);    //  4 MB (16 MB total)

    k_pre<<<dim3(NN / 256), dim3(256), 0, stream>>>(bed, pw, status, melt, area,
                                                    phi, inv, runoff);

    dim3 grid(COLS / TILE_W, ROWS / TILE_H), block(NT);   // 32 x 16 = 512 blocks
    k_fused<true,  false><<<grid, block, 0, stream>>>(phi, inv, runoff, runoff, qA, nullptr, nullptr);
    k_fused<false, true ><<<grid, block, 0, stream>>>(phi, inv, runoff, qA, out, cond, status);
}

// Round 9
// 156.008 us; speedup vs baseline: 1.0034x; 1.0034x over previous
//
#include <hip/hip_runtime.h>

#define ROWS 1024
#define COLS 1024
#define NN (ROWS*COLS)

#define TILE_H 64
#define TILE_W 32
#define HALO   16              // steps fused per launch
#define RH     96              // TILE_H + 2*HALO
#define RW     64              // TILE_W + 2*HALO
#define RC     (RH*RW)         // 6144 cells
#define SPR    (RW/4)          // 16 float4-strips per region row
#define NT     384             // 6 waves; == number of 4x4 blocks
#define BR     (RH/4)          // 24 block-rows
#define BC     (RW/4)          // 16 block-cols

static constexpr float RHOG    = 1000.0f * 9.81f;
static constexpr float INV_SEC = 1.0f / 31556926.0f;
static constexpr float FLOWC   = 0.0405f;

__device__ __forceinline__ float4 gld4(const float* __restrict__ p, int g, bool in) {
    if (in) return *reinterpret_cast<const float4*>(p + g);
    return make_float4(0.f, 0.f, 0.f, 0.f);
}

// ---- prologue: phi, inv_total, runoff -------------------------------------
__global__ __launch_bounds__(256) void k_pre(
        const float* __restrict__ bed, const float* __restrict__ pw,
        const int* __restrict__ status,
        const float* __restrict__ melt, const float* __restrict__ area,
        float* __restrict__ phi, float* __restrict__ inv,
        float* __restrict__ runoff) {
    int i = blockIdx.x * 256 + threadIdx.x;
    int r = i >> 10, c = i & (COLS - 1);
    float p = RHOG * bed[i] + pw[i];
    float t = 0.f;
    if (c > 0)        t += fmaxf(p - (RHOG * bed[i - 1]    + pw[i - 1]),    0.f);
    if (c < COLS - 1) t += fmaxf(p - (RHOG * bed[i + 1]    + pw[i + 1]),    0.f);
    if (r > 0)        t += fmaxf(p - (RHOG * bed[i - COLS] + pw[i - COLS]), 0.f);
    if (r < ROWS - 1) t += fmaxf(p - (RHOG * bed[i + COLS] + pw[i + COLS]), 0.f);
    phi[i]    = p;
    inv[i]    = (status[i] == 0 && t > 0.f) ? (1.f / t) : 0.f;
    runoff[i] = melt[i] * area[i] * INV_SEC;
}

// ---- fused 16-step halo-tiled Jacobi, 4x4 cells/thread --------------------
// R8 post-mortem: (384,3)'s 170-VGPR cap sat right at the ~160-reg live set
// -> partial spills persisted (~40 us/launch, L3-served scratch). R9 diet:
// dd[16]->2 packed uints (s<min(a,b) == (s<a)&(s<b)); nq[16] transient ->
// in-place row rotation (pr/oldrow/nr = 12 regs). Peak ~135 < 170: no spill.
template <bool FIRST, bool FINAL>
__global__ __launch_bounds__(NT, 3) void k_fused(
        const float* __restrict__ phi_g, const float* __restrict__ inv_g,
        const float* __restrict__ run_g, const float* __restrict__ qin,
        float* __restrict__ qout,
        const float* __restrict__ cond, const int* __restrict__ status) {
    __shared__ __align__(16) char smem[8 * NT * 16];   // 49152 B, unioned
    float*  A   = (float*)smem;                        // phi staging [RC]
    float*  Bv  = A + RC;                              // inv staging [RC]
    float4* plT = (float4*)smem;                       // [2][NT] each
    float4* plB = plT + 2 * NT;
    float4* plL = plB + 2 * NT;
    float4* plR = plL + 2 * NT;

    const int tid = threadIdx.x;
    const int r0 = (int)blockIdx.y * TILE_H - HALO;
    const int c0 = (int)blockIdx.x * TILE_W - HALO;

    // phase 1: stage phi, inv (4 strips/thread)
#pragma unroll
    for (int k = 0; k < 4; ++k) {
        int sidx = tid + k * NT;
        int sr = sidx / SPR, sc4 = (sidx - sr * SPR) * 4;
        int gr = r0 + sr, gc = c0 + sc4;
        bool in = (gr >= 0) & (gr < ROWS) & (gc >= 0) & (gc < COLS);
        int g = gr * COLS + gc;
        *reinterpret_cast<float4*>(&A[sr * RW + sc4])  = gld4(phi_g, g, in);
        *reinterpret_cast<float4*>(&Bv[sr * RW + sc4]) = gld4(inv_g, g, in);
    }
    __syncthreads();

    const int br = tid / BC, bc = tid - (tid / BC) * BC;
    const int rr0 = 4 * br, cc0 = 4 * bc;
    const bool inter = (br >= HALO / 4) & (br < BR - HALO / 4) &
                       (bc >= HALO / 4) & (bc < BC - HALO / 4);

    float wW[4][4], wE[4][4], wN[4][4], wS[4][4];
    float q[4][4], ro[4][4];

    // packed border distances: dr byte i = row-depth of row rr0+i, dc byte j
    unsigned dr_pack = 0, dc_pack = 0;
#pragma unroll
    for (int i = 0; i < 4; ++i) {
        unsigned dri = (unsigned)min(rr0 + i, RH - 1 - (rr0 + i));
        unsigned dcj = (unsigned)min(cc0 + i, RW - 1 - (cc0 + i));
        dr_pack |= dri << (8 * i);
        dc_pack |= dcj << (8 * i);
    }

    // phase 2: weights from LDS phi/inv into registers
#pragma unroll
    for (int i = 0; i < 4; ++i) {
        int rr = rr0 + i;
        int x = rr * RW + cc0;
        float4 pc = *reinterpret_cast<const float4*>(&A[x]);
        float4 ic = *reinterpret_cast<const float4*>(&Bv[x]);
        int xu = (rr > 0)      ? x - RW : x;
        int xd = (rr < RH - 1) ? x + RW : x;
        float4 pu = *reinterpret_cast<const float4*>(&A[xu]);
        float4 iu = *reinterpret_cast<const float4*>(&Bv[xu]);
        float4 pd = *reinterpret_cast<const float4*>(&A[xd]);
        float4 id = *reinterpret_cast<const float4*>(&Bv[xd]);
        float pl = (cc0 > 0)      ? A[x - 1]  : pc.x;
        float il = (cc0 > 0)      ? Bv[x - 1] : 0.f;
        float pr_ = (cc0 < RW - 4) ? A[x + 4]  : pc.w;
        float ir = (cc0 < RW - 4) ? Bv[x + 4] : 0.f;
        wN[i][0] = fmaxf(pu.x - pc.x, 0.f) * iu.x;
        wN[i][1] = fmaxf(pu.y - pc.y, 0.f) * iu.y;
        wN[i][2] = fmaxf(pu.z - pc.z, 0.f) * iu.z;
        wN[i][3] = fmaxf(pu.w - pc.w, 0.f) * iu.w;
        wS[i][0] = fmaxf(pd.x - pc.x, 0.f) * id.x;
        wS[i][1] = fmaxf(pd.y - pc.y, 0.f) * id.y;
        wS[i][2] = fmaxf(pd.z - pc.z, 0.f) * id.z;
        wS[i][3] = fmaxf(pd.w - pc.w, 0.f) * id.w;
        wW[i][0] = fmaxf(pl   - pc.x, 0.f) * il;
        wW[i][1] = fmaxf(pc.x - pc.y, 0.f) * ic.x;
        wW[i][2] = fmaxf(pc.y - pc.z, 0.f) * ic.y;
        wW[i][3] = fmaxf(pc.z - pc.w, 0.f) * ic.z;
        wE[i][0] = fmaxf(pc.y - pc.x, 0.f) * ic.y;
        wE[i][1] = fmaxf(pc.z - pc.y, 0.f) * ic.z;
        wE[i][2] = fmaxf(pc.w - pc.z, 0.f) * ic.w;
        wE[i][3] = fmaxf(pr_  - pc.w, 0.f) * ir;
    }
    // runoff + q0 straight from global to registers
#pragma unroll
    for (int i = 0; i < 4; ++i) {
        int gr = r0 + rr0 + i, gc = c0 + cc0;
        bool in = (gr >= 0) & (gr < ROWS) & (gc >= 0) & (gc < COLS);
        int g = gr * COLS + gc;
        float4 r4 = gld4(run_g, g, in);
        ro[i][0] = r4.x; ro[i][1] = r4.y; ro[i][2] = r4.z; ro[i][3] = r4.w;
        float4 q4 = FIRST ? r4 : gld4(qin, g, in);
        q[i][0] = q4.x; q[i][1] = q4.y; q[i][2] = q4.z; q[i][3] = q4.w;
    }
    __syncthreads();   // all phi/inv reads done — safe to overwrite with planes

    plT[tid] = make_float4(q[0][0], q[0][1], q[0][2], q[0][3]);
    plB[tid] = make_float4(q[3][0], q[3][1], q[3][2], q[3][3]);
    plL[tid] = make_float4(q[0][0], q[1][0], q[2][0], q[3][0]);
    plR[tid] = make_float4(q[0][3], q[1][3], q[2][3], q[3][3]);
    __syncthreads();

    // phase 3: 16 Jacobi steps; LDS only at block edges; in-place row update
    for (int s = 0; s < HALO; ++s) {
        const int pp = s & 1, pn = pp ^ 1;
        float4 up = plB[pp * NT + ((br > 0)      ? tid - BC : tid)];
        float4 dn = plT[pp * NT + ((br < BR - 1) ? tid + BC : tid)];
        float4 lf = plR[pp * NT + ((bc > 0)      ? tid - 1  : tid)];
        float4 rt = plL[pp * NT + ((bc < BC - 1) ? tid + 1  : tid)];
        bool fr[4], fc[4];
#pragma unroll
        for (int i = 0; i < 4; ++i) {
            fr[i] = (unsigned)s < ((dr_pack >> (8 * i)) & 0xFFu);
            fc[i] = (unsigned)s < ((dc_pack >> (8 * i)) & 0xFFu);
        }
        float pr[4]  = {up.x, up.y, up.z, up.w};   // old row i-1
        float lfv[4] = {lf.x, lf.y, lf.z, lf.w};
        float rtv[4] = {rt.x, rt.y, rt.z, rt.w};
        float dnv[4] = {dn.x, dn.y, dn.z, dn.w};
#pragma unroll
        for (int i = 0; i < 4; ++i) {
            float oldr[4] = {q[i][0], q[i][1], q[i][2], q[i][3]};
            float nr[4];
#pragma unroll
            for (int j = 0; j < 4; ++j) {
                float uv = pr[j];
                float dv = (i < 3) ? q[i + 1][j] : dnv[j];
                float lv = (j > 0) ? oldr[j - 1] : lfv[i];
                float rv = (j < 3) ? oldr[j + 1] : rtv[i];
                float a = ro[i][j];
                a = fmaf(wW[i][j], lv, a);
                a = fmaf(wE[i][j], rv, a);
                a = fmaf(wN[i][j], uv, a);
                a = fmaf(wS[i][j], dv, a);
                nr[j] = a;
            }
            if (!inter) {      // border blocks freeze cells past their depth
#pragma unroll
                for (int j = 0; j < 4; ++j)
                    nr[j] = (fr[i] && fc[j]) ? nr[j] : oldr[j];
            }
#pragma unroll
            for (int j = 0; j < 4; ++j) { pr[j] = oldr[j]; q[i][j] = nr[j]; }
        }
        plT[pn * NT + tid] = make_float4(q[0][0], q[0][1], q[0][2], q[0][3]);
        plB[pn * NT + tid] = make_float4(q[3][0], q[3][1], q[3][2], q[3][3]);
        plL[pn * NT + tid] = make_float4(q[0][0], q[1][0], q[2][0], q[3][0]);
        plR[pn * NT + tid] = make_float4(q[0][3], q[1][3], q[2][3], q[3][3]);
        __syncthreads();
    }

    // phase 4: interior blocks == the 64x32 output tile exactly
    if (inter) {
#pragma unroll
        for (int i = 0; i < 4; ++i) {
            int g = (r0 + rr0 + i) * COLS + (c0 + cc0);
            if (FINAL) {
                float4 c4 = *reinterpret_cast<const float4*>(cond + g);
                int4 st   = *reinterpret_cast<const int4*>(status + g);
                float4 o;
                float t;
                t = q[i][0] * FLOWC * (c4.x * sqrtf(sqrtf(c4.x))); o.x = (st.x == 0) ? t * t : 0.f;
                t = q[i][1] * FLOWC * (c4.y * sqrtf(sqrtf(c4.y))); o.y = (st.y == 0) ? t * t : 0.f;
                t = q[i][2] * FLOWC * (c4.z * sqrtf(sqrtf(c4.z))); o.z = (st.z == 0) ? t * t : 0.f;
                t = q[i][3] * FLOWC * (c4.w * sqrtf(sqrtf(c4.w))); o.w = (st.w == 0) ? t * t : 0.f;
                *reinterpret_cast<float4*>(qout + g) = o;
            } else {
                *reinterpret_cast<float4*>(qout + g) =
                    make_float4(q[i][0], q[i][1], q[i][2], q[i][3]);
            }
        }
    }
}

extern "C" void kernel_launch(void* const* d_in, const int* in_sizes, int n_in,
                              void* d_out, int out_size, void* d_ws, size_t ws_size,
                              hipStream_t stream) {
    const float* melt   = (const float*)d_in[0];
    const float* bed    = (const float*)d_in[1];
    const float* pw     = (const float*)d_in[2];
    const float* area   = (const float*)d_in[3];
    const float* cond   = (const float*)d_in[4];
    const int*   status = (const int*)d_in[5];
    float* out = (float*)d_out;

    char* ws = (char*)d_ws;
    float* phi    = (float*)(ws);                 //  4 MB
    float* inv    = (float*)(ws + 4ull  * NN);    //  4 MB
    float* runoff = (float*)(ws + 8ull  * NN);    //  4 MB
    float* qA     = (float*)(ws + 12ull * NN);    //  4 MB (16 MB total)

    k_pre<<<dim3(NN / 256), dim3(256), 0, stream>>>(bed, pw, status, melt, area,
                                                    phi, inv, runoff);

    dim3 grid(COLS / TILE_W, ROWS / TILE_H), block(NT);   // 32 x 16 = 512 blocks
    k_fused<true,  false><<<grid, block, 0, stream>>>(phi, inv, runoff, runoff, qA, nullptr, nullptr);
    k_fused<false, true ><<<grid, block, 0, stream>>>(phi, inv, runoff, qA, out, cond, status);
}

// Round 10
// 142.894 us; speedup vs baseline: 1.0955x; 1.0918x over previous
//
#include <hip/hip_runtime.h>

#define ROWS 1024
#define COLS 1024
#define NN (ROWS*COLS)

#define TILE_H 32
#define TILE_W 64
#define HALO   8               // steps fused per launch
#define RH     48              // TILE_H + 2*HALO
#define RW     80              // TILE_W + 2*HALO
#define RC     (RH*RW)         // 3840 cells
#define SPR    (RW/4)          // 20 float4-strips per region row
#define NSTRIP (RC/4)          // 960
#define NT     256
#define BR     (RH/4)          // 12 block-rows of 4x4 cells
#define BC     (RW/4)          // 20 block-cols
#define NB4    (BR*BC)         // 240 active threads

static constexpr float RHOG    = 1000.0f * 9.81f;
static constexpr float INV_SEC = 1.0f / 31556926.0f;
static constexpr float FLOWC   = 0.0405f;

__device__ __forceinline__ float4 gld4(const float* __restrict__ p, int g, bool in) {
    if (in) return *reinterpret_cast<const float4*>(p + g);
    return make_float4(0.f, 0.f, 0.f, 0.f);
}

// ---- prologue: phi, inv_total, runoff -------------------------------------
__global__ __launch_bounds__(256) void k_pre(
        const float* __restrict__ bed, const float* __restrict__ pw,
        const int* __restrict__ status,
        const float* __restrict__ melt, const float* __restrict__ area,
        float* __restrict__ phi, float* __restrict__ inv,
        float* __restrict__ runoff) {
    int i = blockIdx.x * 256 + threadIdx.x;
    int r = i >> 10, c = i & (COLS - 1);
    float p = RHOG * bed[i] + pw[i];
    float t = 0.f;
    if (c > 0)        t += fmaxf(p - (RHOG * bed[i - 1]    + pw[i - 1]),    0.f);
    if (c < COLS - 1) t += fmaxf(p - (RHOG * bed[i + 1]    + pw[i + 1]),    0.f);
    if (r > 0)        t += fmaxf(p - (RHOG * bed[i - COLS] + pw[i - COLS]), 0.f);
    if (r < ROWS - 1) t += fmaxf(p - (RHOG * bed[i + COLS] + pw[i + COLS]), 0.f);
    phi[i]    = p;
    inv[i]    = (status[i] == 0 && t > 0.f) ? (1.f / t) : 0.f;
    runoff[i] = melt[i] * area[i] * INV_SEC;
}

// ---- fused 8-step halo-tiled Jacobi, 4x4 cells/thread ---------------------
// R6 structure (measured best: 141 us) + R7/R8's spill fix applied to it:
// __launch_bounds__(256,2) -> VGPR cap 256 >> ~120-reg live set, no spills;
// 8 waves/CU and 61.4 KB LDS still allow the 2 blocks/CU the grid needs.
// Register diet from R9 kept (packed depths, in-place row rotation).
template <bool FIRST, bool FINAL>
__global__ __launch_bounds__(256, 2) void k_fused(
        const float* __restrict__ phi_g, const float* __restrict__ inv_g,
        const float* __restrict__ run_g, const float* __restrict__ qin,
        float* __restrict__ qout,
        const float* __restrict__ cond, const int* __restrict__ status) {
    __shared__ float A[RC];                      // phi staging  (15360 B)
    __shared__ float Bv[RC];                     // inv staging  (15360 B)
    __shared__ float4 plT[2][NB4], plB[2][NB4];  // top/bottom row planes
    __shared__ float4 plL[2][NB4], plR[2][NB4];  // left/right col planes (30720 B)
    const int tid = threadIdx.x;
    const int r0 = (int)blockIdx.y * TILE_H - HALO;
    const int c0 = (int)blockIdx.x * TILE_W - HALO;

    // phase 1: stage phi, inv (all 256 threads)
#pragma unroll
    for (int k = 0; k < 4; ++k) {
        int sidx = tid + k * NT;
        if (sidx < NSTRIP) {
            int sr = sidx / SPR, sc4 = (sidx - sr * SPR) * 4;
            int gr = r0 + sr, gc = c0 + sc4;
            bool in = (gr >= 0) & (gr < ROWS) & (gc >= 0) & (gc < COLS);
            int g = gr * COLS + gc;
            *reinterpret_cast<float4*>(&A[sr * RW + sc4])  = gld4(phi_g, g, in);
            *reinterpret_cast<float4*>(&Bv[sr * RW + sc4]) = gld4(inv_g, g, in);
        }
    }
    __syncthreads();

    const bool active = (tid < NB4);
    const int br = tid / BC, bc = tid - (tid / BC) * BC;
    const int rr0 = 4 * br, cc0 = 4 * bc;
    const bool inter = (br >= 2) & (br <= BR - 3) & (bc >= 2) & (bc <= BC - 3);

    float wW[4][4], wE[4][4], wN[4][4], wS[4][4];
    float q[4][4], ro[4][4];
    unsigned dr_pack = 0, dc_pack = 0;

    if (active) {
        // packed border distances (byte i = depth of row rr0+i / col cc0+i)
#pragma unroll
        for (int i = 0; i < 4; ++i) {
            unsigned dri = (unsigned)min(rr0 + i, RH - 1 - (rr0 + i));
            unsigned dcj = (unsigned)min(cc0 + i, RW - 1 - (cc0 + i));
            dr_pack |= dri << (8 * i);
            dc_pack |= dcj << (8 * i);
        }
        // phase 2: weights from LDS phi/inv; clamped edge reads yield w=0
#pragma unroll
        for (int i = 0; i < 4; ++i) {
            int rr = rr0 + i;
            int x = rr * RW + cc0;
            float4 pc = *reinterpret_cast<const float4*>(&A[x]);
            float4 ic = *reinterpret_cast<const float4*>(&Bv[x]);
            int xu = (rr > 0)      ? x - RW : x;
            int xd = (rr < RH - 1) ? x + RW : x;
            float4 pu = *reinterpret_cast<const float4*>(&A[xu]);
            float4 iu = *reinterpret_cast<const float4*>(&Bv[xu]);
            float4 pd = *reinterpret_cast<const float4*>(&A[xd]);
            float4 id = *reinterpret_cast<const float4*>(&Bv[xd]);
            float pl  = (cc0 > 0)      ? A[x - 1]  : pc.x;
            float il  = (cc0 > 0)      ? Bv[x - 1] : 0.f;
            float pr_ = (cc0 < RW - 4) ? A[x + 4]  : pc.w;
            float ir  = (cc0 < RW - 4) ? Bv[x + 4] : 0.f;
            wN[i][0] = fmaxf(pu.x - pc.x, 0.f) * iu.x;
            wN[i][1] = fmaxf(pu.y - pc.y, 0.f) * iu.y;
            wN[i][2] = fmaxf(pu.z - pc.z, 0.f) * iu.z;
            wN[i][3] = fmaxf(pu.w - pc.w, 0.f) * iu.w;
            wS[i][0] = fmaxf(pd.x - pc.x, 0.f) * id.x;
            wS[i][1] = fmaxf(pd.y - pc.y, 0.f) * id.y;
            wS[i][2] = fmaxf(pd.z - pc.z, 0.f) * id.z;
            wS[i][3] = fmaxf(pd.w - pc.w, 0.f) * id.w;
            wW[i][0] = fmaxf(pl   - pc.x, 0.f) * il;
            wW[i][1] = fmaxf(pc.x - pc.y, 0.f) * ic.x;
            wW[i][2] = fmaxf(pc.y - pc.z, 0.f) * ic.y;
            wW[i][3] = fmaxf(pc.z - pc.w, 0.f) * ic.z;
            wE[i][0] = fmaxf(pc.y - pc.x, 0.f) * ic.y;
            wE[i][1] = fmaxf(pc.z - pc.y, 0.f) * ic.z;
            wE[i][2] = fmaxf(pc.w - pc.z, 0.f) * ic.w;
            wE[i][3] = fmaxf(pr_  - pc.w, 0.f) * ir;
        }
        // runoff + q0 straight from global to registers
#pragma unroll
        for (int i = 0; i < 4; ++i) {
            int gr = r0 + rr0 + i, gc = c0 + cc0;
            bool in = (gr >= 0) & (gr < ROWS) & (gc >= 0) & (gc < COLS);
            int g = gr * COLS + gc;
            float4 r4 = gld4(run_g, g, in);
            ro[i][0] = r4.x; ro[i][1] = r4.y; ro[i][2] = r4.z; ro[i][3] = r4.w;
            float4 q4 = FIRST ? r4 : gld4(qin, g, in);
            q[i][0] = q4.x; q[i][1] = q4.y; q[i][2] = q4.z; q[i][3] = q4.w;
        }
        plT[0][tid] = make_float4(q[0][0], q[0][1], q[0][2], q[0][3]);
        plB[0][tid] = make_float4(q[3][0], q[3][1], q[3][2], q[3][3]);
        plL[0][tid] = make_float4(q[0][0], q[1][0], q[2][0], q[3][0]);
        plR[0][tid] = make_float4(q[0][3], q[1][3], q[2][3], q[3][3]);
    }
    __syncthreads();

    // phase 3: 8 Jacobi steps; LDS only at block edges; in-place row update
    for (int s = 0; s < HALO; ++s) {
        const int pp = s & 1, pn = pp ^ 1;
        if (active) {
            float4 up = plB[pp][(br > 0)      ? tid - BC : tid];
            float4 dn = plT[pp][(br < BR - 1) ? tid + BC : tid];
            float4 lf = plR[pp][(bc > 0)      ? tid - 1  : tid];
            float4 rt = plL[pp][(bc < BC - 1) ? tid + 1  : tid];
            bool fr[4], fc[4];
#pragma unroll
            for (int i = 0; i < 4; ++i) {
                fr[i] = (unsigned)s < ((dr_pack >> (8 * i)) & 0xFFu);
                fc[i] = (unsigned)s < ((dc_pack >> (8 * i)) & 0xFFu);
            }
            float pr[4]  = {up.x, up.y, up.z, up.w};   // old row i-1
            float lfv[4] = {lf.x, lf.y, lf.z, lf.w};
            float rtv[4] = {rt.x, rt.y, rt.z, rt.w};
            float dnv[4] = {dn.x, dn.y, dn.z, dn.w};
#pragma unroll
            for (int i = 0; i < 4; ++i) {
                float oldr[4] = {q[i][0], q[i][1], q[i][2], q[i][3]};
                float nr[4];
#pragma unroll
                for (int j = 0; j < 4; ++j) {
                    float uv = pr[j];
                    float dv = (i < 3) ? q[i + 1][j] : dnv[j];
                    float lv = (j > 0) ? oldr[j - 1] : lfv[i];
                    float rv = (j < 3) ? oldr[j + 1] : rtv[i];
                    float a = ro[i][j];
                    a = fmaf(wW[i][j], lv, a);
                    a = fmaf(wE[i][j], rv, a);
                    a = fmaf(wN[i][j], uv, a);
                    a = fmaf(wS[i][j], dv, a);
                    nr[j] = a;
                }
                if (!inter) {  // border blocks freeze cells past their depth
#pragma unroll
                    for (int j = 0; j < 4; ++j)
                        nr[j] = (fr[i] && fc[j]) ? nr[j] : oldr[j];
                }
#pragma unroll
                for (int j = 0; j < 4; ++j) { pr[j] = oldr[j]; q[i][j] = nr[j]; }
            }
            plT[pn][tid] = make_float4(q[0][0], q[0][1], q[0][2], q[0][3]);
            plB[pn][tid] = make_float4(q[3][0], q[3][1], q[3][2], q[3][3]);
            plL[pn][tid] = make_float4(q[0][0], q[1][0], q[2][0], q[3][0]);
            plR[pn][tid] = make_float4(q[0][3], q[1][3], q[2][3], q[3][3]);
        }
        __syncthreads();
    }

    // phase 4: interior blocks == the 32x64 output tile exactly
    if (active && inter) {
#pragma unroll
        for (int i = 0; i < 4; ++i) {
            int g = (r0 + rr0 + i) * COLS + (c0 + cc0);
            if (FINAL) {
                float4 c4 = *reinterpret_cast<const float4*>(cond + g);
                int4 st   = *reinterpret_cast<const int4*>(status + g);
                float4 o;
                float t;
                t = q[i][0] * FLOWC * (c4.x * sqrtf(sqrtf(c4.x))); o.x = (st.x == 0) ? t * t : 0.f;
                t = q[i][1] * FLOWC * (c4.y * sqrtf(sqrtf(c4.y))); o.y = (st.y == 0) ? t * t : 0.f;
                t = q[i][2] * FLOWC * (c4.z * sqrtf(sqrtf(c4.z))); o.z = (st.z == 0) ? t * t : 0.f;
                t = q[i][3] * FLOWC * (c4.w * sqrtf(sqrtf(c4.w))); o.w = (st.w == 0) ? t * t : 0.f;
                *reinterpret_cast<float4*>(qout + g) = o;
            } else {
                *reinterpret_cast<float4*>(qout + g) =
                    make_float4(q[i][0], q[i][1], q[i][2], q[i][3]);
            }
        }
    }
}

extern "C" void kernel_launch(void* const* d_in, const int* in_sizes, int n_in,
                              void* d_out, int out_size, void* d_ws, size_t ws_size,
                              hipStream_t stream) {
    const float* melt   = (const float*)d_in[0];
    const float* bed    = (const float*)d_in[1];
    const float* pw     = (const float*)d_in[2];
    const float* area   = (const float*)d_in[3];
    const float* cond   = (const float*)d_in[4];
    const int*   status = (const int*)d_in[5];
    float* out = (float*)d_out;

    char* ws = (char*)d_ws;
    float* phi    = (float*)(ws);                 //  4 MB
    float* inv    = (float*)(ws + 4ull  * NN);    //  4 MB
    float* runoff = (float*)(ws + 8ull  * NN);    //  4 MB
    float* qA     = (float*)(ws + 12ull * NN);    //  4 MB
    float* qB     = (float*)(ws + 16ull * NN);    //  4 MB (20 MB total)

    k_pre<<<dim3(NN / 256), dim3(256), 0, stream>>>(bed, pw, status, melt, area,
                                                    phi, inv, runoff);

    dim3 grid(COLS / TILE_W, ROWS / TILE_H), block(NT);   // 16 x 32 = 512 blocks
    k_fused<true,  false><<<grid, block, 0, stream>>>(phi, inv, runoff, runoff, qA, nullptr, nullptr);
    k_fused<false, false><<<grid, block, 0, stream>>>(phi, inv, runoff, qA, qB, nullptr, nullptr);
    k_fused<false, false><<<grid, block, 0, stream>>>(phi, inv, runoff, qB, qA, nullptr, nullptr);
    k_fused<false, true ><<<grid, block, 0, stream>>>(phi, inv, runoff, qA, out, cond, status);
}

// Round 11
// 141.727 us; speedup vs baseline: 1.1045x; 1.0082x over previous
//
#include <hip/hip_runtime.h>

#define ROWS 1024
#define COLS 1024
#define NN (ROWS*COLS)

#define TILE_H 32
#define TILE_W 64
#define HALO   8               // steps fused per launch
#define RH     48              // TILE_H + 2*HALO
#define RW     80              // TILE_W + 2*HALO
#define RC     (RH*RW)         // 3840 cells
#define SPR    (RW/4)          // 20 float4-strips per region row
#define NSTRIP (RC/4)          // 960
#define NT     256
#define BR     (RH/4)          // 12 block-rows of 4x4 cells
#define BC     (RW/4)          // 20 block-cols
#define NB4    (BR*BC)         // 240 active threads

static constexpr float RHOG    = 1000.0f * 9.81f;
static constexpr float INV_SEC = 1.0f / 31556926.0f;
static constexpr float FLOWC   = 0.0405f;

// Branchless: unconditional load from clamped address, then select.
// (R10 post-mortem: `if (in) load` exec-branches serialized the staging
// loads; this form issues them all back-to-back.)
__device__ __forceinline__ float4 gld4c(const float* __restrict__ p, int g, bool in) {
    float4 v = *reinterpret_cast<const float4*>(p + (in ? g : 0));
    return in ? v : make_float4(0.f, 0.f, 0.f, 0.f);
}

// ---- prologue: phi, inv_total, runoff -------------------------------------
__global__ __launch_bounds__(256) void k_pre(
        const float* __restrict__ bed, const float* __restrict__ pw,
        const int* __restrict__ status,
        const float* __restrict__ melt, const float* __restrict__ area,
        float* __restrict__ phi, float* __restrict__ inv,
        float* __restrict__ runoff) {
    int i = blockIdx.x * 256 + threadIdx.x;
    int r = i >> 10, c = i & (COLS - 1);
    float p = RHOG * bed[i] + pw[i];
    float t = 0.f;
    if (c > 0)        t += fmaxf(p - (RHOG * bed[i - 1]    + pw[i - 1]),    0.f);
    if (c < COLS - 1) t += fmaxf(p - (RHOG * bed[i + 1]    + pw[i + 1]),    0.f);
    if (r > 0)        t += fmaxf(p - (RHOG * bed[i - COLS] + pw[i - COLS]), 0.f);
    if (r < ROWS - 1) t += fmaxf(p - (RHOG * bed[i + COLS] + pw[i + COLS]), 0.f);
    phi[i]    = p;
    inv[i]    = (status[i] == 0 && t > 0.f) ? (1.f / t) : 0.f;
    runoff[i] = melt[i] * area[i] * INV_SEC;
}

// ---- fused 8-step halo-tiled Jacobi, 4x4 cells/thread ---------------------
// R6/R10 structure; R11: all global loads issued branchlessly and up-front
// (phi/inv strips + runoff/q0) before any LDS write/barrier, so the whole
// staging set overlaps one memory round-trip.
template <bool FIRST, bool FINAL>
__global__ __launch_bounds__(256, 2) void k_fused(
        const float* __restrict__ phi_g, const float* __restrict__ inv_g,
        const float* __restrict__ run_g, const float* __restrict__ qin,
        float* __restrict__ qout,
        const float* __restrict__ cond, const int* __restrict__ status) {
    __shared__ float A[RC];                      // phi staging  (15360 B)
    __shared__ float Bv[RC];                     // inv staging  (15360 B)
    __shared__ float4 plT[2][NB4], plB[2][NB4];  // top/bottom row planes
    __shared__ float4 plL[2][NB4], plR[2][NB4];  // left/right col planes (30720 B)
    const int tid = threadIdx.x;
    const int r0 = (int)blockIdx.y * TILE_H - HALO;
    const int c0 = (int)blockIdx.x * TILE_W - HALO;

    const bool active = (tid < NB4);
    const int br = tid / BC, bc = tid - (tid / BC) * BC;
    const int rr0 = 4 * br, cc0 = 4 * bc;
    const bool inter = (br >= 2) & (br <= BR - 3) & (bc >= 2) & (bc <= BC - 3);

    // ---- phase 0: issue ALL global loads first (branchless) ----
    float4 sP[4], sI[4];
    int sx[4];
    bool sv[4];
#pragma unroll
    for (int k = 0; k < 4; ++k) {
        int sidx = tid + k * NT;
        bool valid = (sidx < NSTRIP);
        int sr = sidx / SPR, sc4 = (sidx - sr * SPR) * 4;
        int gr = r0 + sr, gc = c0 + sc4;
        bool in = valid & (gr >= 0) & (gr < ROWS) & (gc >= 0) & (gc < COLS);
        int g = gr * COLS + gc;
        sx[k] = sr * RW + sc4;
        sv[k] = valid;
        sP[k] = gld4c(phi_g, g, in);
        sI[k] = gld4c(inv_g, g, in);
    }
    float q[4][4], ro[4][4];
#pragma unroll
    for (int i = 0; i < 4; ++i) {
        int gr = r0 + rr0 + i, gc = c0 + cc0;
        bool in = active & (gr >= 0) & (gr < ROWS) & (gc >= 0) & (gc < COLS);
        int g = gr * COLS + gc;
        float4 r4 = gld4c(run_g, g, in);
        ro[i][0] = r4.x; ro[i][1] = r4.y; ro[i][2] = r4.z; ro[i][3] = r4.w;
        float4 q4 = FIRST ? r4 : gld4c(qin, g, in);
        q[i][0] = q4.x; q[i][1] = q4.y; q[i][2] = q4.z; q[i][3] = q4.w;
    }

    // ---- phase 1: write phi/inv staging to LDS ----
#pragma unroll
    for (int k = 0; k < 4; ++k) {
        if (sv[k]) {
            *reinterpret_cast<float4*>(&A[sx[k]])  = sP[k];
            *reinterpret_cast<float4*>(&Bv[sx[k]]) = sI[k];
        }
    }
    __syncthreads();

    float wW[4][4], wE[4][4], wN[4][4], wS[4][4];
    unsigned dr_pack = 0, dc_pack = 0;

    if (active) {
        // packed border distances (byte i = depth of row rr0+i / col cc0+i)
#pragma unroll
        for (int i = 0; i < 4; ++i) {
            unsigned dri = (unsigned)min(rr0 + i, RH - 1 - (rr0 + i));
            unsigned dcj = (unsigned)min(cc0 + i, RW - 1 - (cc0 + i));
            dr_pack |= dri << (8 * i);
            dc_pack |= dcj << (8 * i);
        }
        // ---- phase 2: weights from LDS phi/inv; clamped edges yield w=0 ----
#pragma unroll
        for (int i = 0; i < 4; ++i) {
            int rr = rr0 + i;
            int x = rr * RW + cc0;
            float4 pc = *reinterpret_cast<const float4*>(&A[x]);
            float4 ic = *reinterpret_cast<const float4*>(&Bv[x]);
            int xu = (rr > 0)      ? x - RW : x;
            int xd = (rr < RH - 1) ? x + RW : x;
            float4 pu = *reinterpret_cast<const float4*>(&A[xu]);
            float4 iu = *reinterpret_cast<const float4*>(&Bv[xu]);
            float4 pd = *reinterpret_cast<const float4*>(&A[xd]);
            float4 id = *reinterpret_cast<const float4*>(&Bv[xd]);
            float pl  = (cc0 > 0)      ? A[x - 1]  : pc.x;
            float il  = (cc0 > 0)      ? Bv[x - 1] : 0.f;
            float pr_ = (cc0 < RW - 4) ? A[x + 4]  : pc.w;
            float ir  = (cc0 < RW - 4) ? Bv[x + 4] : 0.f;
            wN[i][0] = fmaxf(pu.x - pc.x, 0.f) * iu.x;
            wN[i][1] = fmaxf(pu.y - pc.y, 0.f) * iu.y;
            wN[i][2] = fmaxf(pu.z - pc.z, 0.f) * iu.z;
            wN[i][3] = fmaxf(pu.w - pc.w, 0.f) * iu.w;
            wS[i][0] = fmaxf(pd.x - pc.x, 0.f) * id.x;
            wS[i][1] = fmaxf(pd.y - pc.y, 0.f) * id.y;
            wS[i][2] = fmaxf(pd.z - pc.z, 0.f) * id.z;
            wS[i][3] = fmaxf(pd.w - pc.w, 0.f) * id.w;
            wW[i][0] = fmaxf(pl   - pc.x, 0.f) * il;
            wW[i][1] = fmaxf(pc.x - pc.y, 0.f) * ic.x;
            wW[i][2] = fmaxf(pc.y - pc.z, 0.f) * ic.y;
            wW[i][3] = fmaxf(pc.z - pc.w, 0.f) * ic.z;
            wE[i][0] = fmaxf(pc.y - pc.x, 0.f) * ic.y;
            wE[i][1] = fmaxf(pc.z - pc.y, 0.f) * ic.z;
            wE[i][2] = fmaxf(pc.w - pc.z, 0.f) * ic.w;
            wE[i][3] = fmaxf(pr_  - pc.w, 0.f) * ir;
        }
        plT[0][tid] = make_float4(q[0][0], q[0][1], q[0][2], q[0][3]);
        plB[0][tid] = make_float4(q[3][0], q[3][1], q[3][2], q[3][3]);
        plL[0][tid] = make_float4(q[0][0], q[1][0], q[2][0], q[3][0]);
        plR[0][tid] = make_float4(q[0][3], q[1][3], q[2][3], q[3][3]);
    }
    __syncthreads();

    // ---- phase 3: 8 Jacobi steps; LDS only at block edges ----
    for (int s = 0; s < HALO; ++s) {
        const int pp = s & 1, pn = pp ^ 1;
        if (active) {
            float4 up = plB[pp][(br > 0)      ? tid - BC : tid];
            float4 dn = plT[pp][(br < BR - 1) ? tid + BC : tid];
            float4 lf = plR[pp][(bc > 0)      ? tid - 1  : tid];
            float4 rt = plL[pp][(bc < BC - 1) ? tid + 1  : tid];
            bool fr[4], fc[4];
#pragma unroll
            for (int i = 0; i < 4; ++i) {
                fr[i] = (unsigned)s < ((dr_pack >> (8 * i)) & 0xFFu);
                fc[i] = (unsigned)s < ((dc_pack >> (8 * i)) & 0xFFu);
            }
            float pr[4]  = {up.x, up.y, up.z, up.w};   // old row i-1
            float lfv[4] = {lf.x, lf.y, lf.z, lf.w};
            float rtv[4] = {rt.x, rt.y, rt.z, rt.w};
            float dnv[4] = {dn.x, dn.y, dn.z, dn.w};
#pragma unroll
            for (int i = 0; i < 4; ++i) {
                float oldr[4] = {q[i][0], q[i][1], q[i][2], q[i][3]};
                float nr[4];
#pragma unroll
                for (int j = 0; j < 4; ++j) {
                    float uv = pr[j];
                    float dv = (i < 3) ? q[i + 1][j] : dnv[j];
                    float lv = (j > 0) ? oldr[j - 1] : lfv[i];
                    float rv = (j < 3) ? oldr[j + 1] : rtv[i];
                    float a = ro[i][j];
                    a = fmaf(wW[i][j], lv, a);
                    a = fmaf(wE[i][j], rv, a);
                    a = fmaf(wN[i][j], uv, a);
                    a = fmaf(wS[i][j], dv, a);
                    nr[j] = a;
                }
                if (!inter) {  // border blocks freeze cells past their depth
#pragma unroll
                    for (int j = 0; j < 4; ++j)
                        nr[j] = (fr[i] && fc[j]) ? nr[j] : oldr[j];
                }
#pragma unroll
                for (int j = 0; j < 4; ++j) { pr[j] = oldr[j]; q[i][j] = nr[j]; }
            }
            plT[pn][tid] = make_float4(q[0][0], q[0][1], q[0][2], q[0][3]);
            plB[pn][tid] = make_float4(q[3][0], q[3][1], q[3][2], q[3][3]);
            plL[pn][tid] = make_float4(q[0][0], q[1][0], q[2][0], q[3][0]);
            plR[pn][tid] = make_float4(q[0][3], q[1][3], q[2][3], q[3][3]);
        }
        __syncthreads();
    }

    // ---- phase 4: interior blocks == the 32x64 output tile exactly ----
    if (active && inter) {
#pragma unroll
        for (int i = 0; i < 4; ++i) {
            int g = (r0 + rr0 + i) * COLS + (c0 + cc0);
            if (FINAL) {
                float4 c4 = *reinterpret_cast<const float4*>(cond + g);
                int4 st   = *reinterpret_cast<const int4*>(status + g);
                float4 o;
                float t;
                t = q[i][0] * FLOWC * (c4.x * sqrtf(sqrtf(c4.x))); o.x = (st.x == 0) ? t * t : 0.f;
                t = q[i][1] * FLOWC * (c4.y * sqrtf(sqrtf(c4.y))); o.y = (st.y == 0) ? t * t : 0.f;
                t = q[i][2] * FLOWC * (c4.z * sqrtf(sqrtf(c4.z))); o.z = (st.z == 0) ? t * t : 0.f;
                t = q[i][3] * FLOWC * (c4.w * sqrtf(sqrtf(c4.w))); o.w = (st.w == 0) ? t * t : 0.f;
                *reinterpret_cast<float4*>(qout + g) = o;
            } else {
                *reinterpret_cast<float4*>(qout + g) =
                    make_float4(q[i][0], q[i][1], q[i][2], q[i][3]);
            }
        }
    }
}

extern "C" void kernel_launch(void* const* d_in, const int* in_sizes, int n_in,
                              void* d_out, int out_size, void* d_ws, size_t ws_size,
                              hipStream_t stream) {
    const float* melt   = (const float*)d_in[0];
    const float* bed    = (const float*)d_in[1];
    const float* pw     = (const float*)d_in[2];
    const float* area   = (const float*)d_in[3];
    const float* cond   = (const float*)d_in[4];
    const int*   status = (const int*)d_in[5];
    float* out = (float*)d_out;

    char* ws = (char*)d_ws;
    float* phi    = (float*)(ws);                 //  4 MB
    float* inv    = (float*)(ws + 4ull  * NN);    //  4 MB
    float* runoff = (float*)(ws + 8ull  * NN);    //  4 MB
    float* qA     = (float*)(ws + 12ull * NN);    //  4 MB
    float* qB     = (float*)(ws + 16ull * NN);    //  4 MB (20 MB total)

    k_pre<<<dim3(NN / 256), dim3(256), 0, stream>>>(bed, pw, status, melt, area,
                                                    phi, inv, runoff);

    dim3 grid(COLS / TILE_W, ROWS / TILE_H), block(NT);   // 16 x 32 = 512 blocks
    k_fused<true,  false><<<grid, block, 0, stream>>>(phi, inv, runoff, runoff, qA, nullptr, nullptr);
    k_fused<false, false><<<grid, block, 0, stream>>>(phi, inv, runoff, qA, qB, nullptr, nullptr);
    k_fused<false, false><<<grid, block, 0, stream>>>(phi, inv, runoff, qB, qA, nullptr, nullptr);
    k_fused<false, true ><<<grid, block, 0, stream>>>(phi, inv, runoff, qA, out, cond, status);
}